// Round 4
// baseline (227.152 us; speedup 1.0000x reference)
//
#include <hip/hip_runtime.h>

// HarmonicMixing closed form per row of D=1024 channels (all gathers read the
// ORIGINAL x):
//   out[j] = x[j]
//          + sum_{o=1..3, s=2^o} ( [j%s==0] * sig(uw[o]) * x[j/s]        (up)
//                                 + [1<=j<D/s] * sig(dw[o]) * W_s[j] )   (down)
// W_s via register-side pair-sum hierarchy (S1/S2/S3), conflict-free LDS.
//
// Round-2 lesson: one-row blocks were latency-bound (load -> barrier -> store
// serializes HBM latency per 4KB block). This version: 16 rows per block,
// double-buffered LDS, next-row load issued before the barrier (software
// pipeline), nontemporal streaming loads/stores.
// Round-3 fix: __builtin_nontemporal_* needs a clang ext_vector_type, not
// HIP_vector_type<float,4>.

constexpr int D = 1024;
constexpr int ROWS = 16;   // rows per block -> grid 2048 = 8 resident blocks/CU

typedef float v4f __attribute__((ext_vector_type(4)));
typedef float v2f __attribute__((ext_vector_type(2)));

__global__ __launch_bounds__(256) void harmonic_kernel(
    const float* __restrict__ x,
    const float* __restrict__ uwp,
    const float* __restrict__ dwp,
    float* __restrict__ out)
{
    __shared__ float rowlo[2][512];
    __shared__ float S1[2][512];
    __shared__ float S2[2][256];
    __shared__ float S3[2][128];

    const int t = threadIdx.x;
    const int j0 = t * 4;

    const float uw0 = 1.f / (1.f + __expf(-uwp[0]));
    const float uw1 = 1.f / (1.f + __expf(-uwp[1]));
    const float uw2 = 1.f / (1.f + __expf(-uwp[2]));
    const float dw0 = 1.f / (1.f + __expf(-dwp[0]));
    const float dw1 = 1.f / (1.f + __expf(-dwp[1]));
    const float dw2 = 1.f / (1.f + __expf(-dwp[2]));

    const long long row0 = (long long)blockIdx.x * ROWS;
    const float* xp = x + row0 * D + j0;
    float* op = out + row0 * D + j0;

    v4f v = __builtin_nontemporal_load(reinterpret_cast<const v4f*>(xp));

    for (int r = 0; r < ROWS; ++r) {
        const int b = r & 1;

        // ---- stage current row into LDS (all stride-1 / cheap-alias) ----
        const float s1a = v.x + v.y;               // S1[2t]
        const float s1b = v.z + v.w;               // S1[2t+1]
        const float s2  = s1a + s1b;               // S2[t]
        const float s3  = s2 + __shfl_xor(s2, 1);  // S3[t>>1] (valid on even t)

        if (t < 128) *reinterpret_cast<v4f*>(&rowlo[b][j0]) = v;
        v2f s1v; s1v.x = s1a; s1v.y = s1b;
        *reinterpret_cast<v2f*>(&S1[b][2 * t]) = s1v;
        S2[b][t] = s2;
        if ((t & 1) == 0) S3[b][t >> 1] = s3;

        // ---- prefetch next row BEFORE the barrier (overlap HBM latency) ----
        v4f vn;
        if (r + 1 < ROWS)
            vn = __builtin_nontemporal_load(
                reinterpret_cast<const v4f*>(xp + (long long)(r + 1) * D));

        __syncthreads();

        // ---- compute ----
        v4f res = v;

        // up: out[j] += uw_o * x[j >> o] for j % 2^o == 0
        const v2f u01 = *reinterpret_cast<const v2f*>(&rowlo[b][2 * t]);
        res.x += uw0 * u01.x;
        res.z += uw0 * u01.y;
        res.x += uw1 * rowlo[b][t];
        if ((t & 1) == 0) res.x += uw2 * rowlo[b][t >> 1];

        // down: out[j] += dw_o * S_o[j], 1 <= j < D/2^o  (stride-1 b128)
        if (t < 128) {
            const v4f a = *reinterpret_cast<const v4f*>(&S1[b][j0]);
            if (t > 0) res.x += dw0 * a.x;   // j=0 excluded
            res.y += dw0 * a.y;
            res.z += dw0 * a.z;
            res.w += dw0 * a.w;
            if (t < 64) {
                const v4f c = *reinterpret_cast<const v4f*>(&S2[b][j0]);
                if (t > 0) res.x += dw1 * c.x;
                res.y += dw1 * c.y;
                res.z += dw1 * c.z;
                res.w += dw1 * c.w;
                if (t < 32) {
                    const v4f e = *reinterpret_cast<const v4f*>(&S3[b][j0]);
                    if (t > 0) res.x += dw2 * e.x;
                    res.y += dw2 * e.y;
                    res.z += dw2 * e.z;
                    res.w += dw2 * e.w;
                }
            }
        }

        __builtin_nontemporal_store(res,
            reinterpret_cast<v4f*>(op + (long long)r * D));

        v = vn;
        // no second barrier needed: buffer b is next overwritten only after
        // barrier(r+1), and every thread's reads of buffer b precede its
        // arrival at barrier(r+1) in program order.
    }
}

extern "C" void kernel_launch(void* const* d_in, const int* in_sizes, int n_in,
                              void* d_out, int out_size, void* d_ws, size_t ws_size,
                              hipStream_t stream) {
    const float* x   = (const float*)d_in[0];
    const float* uwp = (const float*)d_in[1];
    const float* dwp = (const float*)d_in[2];
    float* out = (float*)d_out;
    const int n_rows = in_sizes[0] / D;        // 8 * 4096 = 32768
    const int n_blocks = n_rows / ROWS;        // 2048
    harmonic_kernel<<<n_blocks, 256, 0, stream>>>(x, uwp, dwp, out);
}